// Round 3
// baseline (229.429 us; speedup 1.0000x reference)
//
#include <hip/hip_runtime.h>
#include <hip/hip_bf16.h>

#define N_NODES 50000
#define KK 32
#define EE 128
#define NK (N_NODES * KK)
#define NE (N_NODES * EE)
#define WAVES 4
#define PR 32   // rows per GEMM block

typedef __hip_bfloat16 bf16;
typedef unsigned int u32;
typedef unsigned short u16;
typedef __attribute__((ext_vector_type(8))) short bf16x8;
typedef __attribute__((ext_vector_type(4))) float f32x4;

__device__ __forceinline__ float bflo(u32 u) { return __uint_as_float(u << 16); }
__device__ __forceinline__ float bfhi(u32 u) { return __uint_as_float(u & 0xFFFF0000u); }
__device__ __forceinline__ u16 f2bu(float x) {
    union { bf16 b; u16 u; } c; c.b = __float2bfloat16(x); return c.u;
}
__device__ __forceinline__ u32 packbf2(float lo, float hi) {
    return (u32)f2bu(lo) | ((u32)f2bu(hi) << 16);
}

// ---------------------------------------------------------------------------
// Merged prep+pack (R9): blocks 0..255 compute A=WhL@Wf / B=WhR@Wf elements
// and write Wghp frag layout DIRECTLY (each thread owns exactly one frag
// element); blocks 256..319 pack Wstp from Ws; block 320 builds the Wp
// B-fragments (hi/lo bf16 split so Wp keeps f32 accuracy in the MFMA dot).
// grid 321, block 128.
// ---------------------------------------------------------------------------
__global__ void prep_pack(const float* __restrict__ Wh, const float* __restrict__ Wf,
                          const float* __restrict__ bfv, const float* __restrict__ bh,
                          const float* __restrict__ Ws, const float* __restrict__ Wp,
                          u16* __restrict__ Wghp, u16* __restrict__ Wstp,
                          u16* __restrict__ Wpf, float* agf, float* bh2f) {
    int bx = blockIdx.x;
    int tid = threadIdx.x;
    if (bx < 256) {
        int m = bx >> 7;
        int r = bx & 127;
        int c = tid;
        const float* whrow = Wh + (long)r * (2 * EE) + m * EE;
        float acc = 0.f;
        for (int j = 0; j < EE; ++j)
            acc += whrow[j] * Wf[(long)j * EE + c];
        // frag coords: K-index k=c, N-index j=m*128+r
        int jt = (m * EE + r) >> 4, col = r & 15;
        int t = c >> 5, quad = (c >> 3) & 3, jj = c & 7;
        Wghp[((long)(t * 16 + jt)) * 512 + (quad * 16 + col) * 8 + jj] = f2bu(acc);
        if (c == 0) {
            float accb = 0.f;
            for (int j = 0; j < EE; ++j) accb += whrow[j] * bfv[j];
            if (m) bh2f[r] = accb + bh[r];
            else   agf[r] = accb;
        }
    } else if (bx < 320) {
        int bb = bx - 256, t = bb >> 3, jt = bb & 7;
        for (int f = tid; f < 512; f += 128) {
            int lane = f >> 3, jj = f & 7;
            int col = lane & 15, quad = lane >> 4;
            int r = jt * 16 + col;
            int c = t * 32 + quad * 8 + jj;
            Wstp[(long)bb * 512 + f] = f2bu(Ws[(long)r * (2 * EE) + c]);
        }
    } else {
        // Wp B-frags: [s(hi/lo)][t(0..3)][lane][jj]; only col==0 nonzero.
        for (int idx = tid; idx < 4096; idx += 128) {
            int s = idx >> 11, t = (idx >> 9) & 3, lane = (idx >> 3) & 63, jj = idx & 7;
            int col = lane & 15, quad = lane >> 4;
            float v = 0.f;
            if (col == 0) {
                float w = Wp[t * 32 + quad * 8 + jj];
                if (s == 0) v = w;
                else {
                    union { u32 u; float f; } cv;
                    cv.u = ((u32)f2bu(w)) << 16;
                    v = w - cv.f;          // residual -> Wp effectively f32
                }
            }
            Wpf[(long)s * 2048 + t * 512 + lane * 8 + jj] = f2bu(v);
        }
    }
}

// ---------------------------------------------------------------------------
// Distance MLP: d(x) = sum_e W2[e]*relu(W1[e]*x + b1[e]) + b2.
// d written f32 into the out_position region of d_out.
// ---------------------------------------------------------------------------
__global__ __launch_bounds__(256) void dist_mlp(const float* __restrict__ dists,
                                                const float* __restrict__ W1,
                                                const float* __restrict__ b1,
                                                const float* __restrict__ W2,
                                                const float* __restrict__ b2v,
                                                float* __restrict__ dst) {
    __shared__ float4 w4[EE];
    int tid = threadIdx.x;
    if (tid < EE) w4[tid] = make_float4(W1[tid], b1[tid], W2[tid], 0.f);
    __syncthreads();
    float b2s = b2v[0];
    int i0 = (blockIdx.x * 256 + tid) * 4;
    float x[4], acc[4];
    #pragma unroll
    for (int j = 0; j < 4; ++j) {
        int i = i0 + j;
        x[j] = (i < NK) ? dists[i] : 0.f;
        acc[j] = b2s;
    }
    for (int e = 0; e < EE; ++e) {
        float4 w = w4[e];
        #pragma unroll
        for (int j = 0; j < 4; ++j)
            acc[j] += w.z * fmaxf(w.x * x[j] + w.y, 0.f);
    }
    #pragma unroll
    for (int j = 0; j < 4; ++j) {
        int i = i0 + j;
        if (i < NK) dst[i] = acc[j];
    }
}

// ---------------------------------------------------------------------------
// MFMA GEMM: [g|h2] = feature @ [A;B]^T + bias  -> bf16 into out_structure
// region. Block: 32 rows x 256 cols, 4 waves x (2 m-tiles x 4 j-tiles).
// Feature staged bf16 in LDS, row stride 68 u32 (2-way bank alias = free).
// grid ceil(N/32), block 256.
// ---------------------------------------------------------------------------
__global__ __launch_bounds__(256) void proj_gh_mfma(const float* __restrict__ feature,
                                                    const u16* __restrict__ Wghp,
                                                    const float* __restrict__ agf,
                                                    const float* __restrict__ bh2f,
                                                    u16* __restrict__ g,
                                                    u16* __restrict__ h2) {
    __shared__ u32 ft[PR * 68];
    int tid = threadIdx.x;
    int n0 = blockIdx.x * PR;
    for (int idx = tid; idx < PR * 32; idx += 256) {   // float4 units, 32/row
        int rr = idx >> 5, c4 = idx & 31;
        long row = n0 + rr; if (row >= N_NODES) row = N_NODES - 1;
        float4 v = ((const float4*)(feature + row * EE))[c4];
        ft[rr * 68 + 2 * c4]     = packbf2(v.x, v.y);
        ft[rr * 68 + 2 * c4 + 1] = packbf2(v.z, v.w);
    }
    __syncthreads();
    int lane = tid & 63, wave = tid >> 6;
    int col = lane & 15, quad = lane >> 4;
    f32x4 acc[2][4] = {};
    #pragma unroll
    for (int t = 0; t < 4; ++t) {
        bf16x8 a0 = *(const bf16x8*)&ft[col * 68 + t * 16 + quad * 4];
        bf16x8 a1 = *(const bf16x8*)&ft[(16 + col) * 68 + t * 16 + quad * 4];
        #pragma unroll
        for (int jt = 0; jt < 4; ++jt) {
            int jtg = wave * 4 + jt;
            bf16x8 b = *(const bf16x8*)&Wghp[((long)(t * 16 + jtg) * 64 + lane) * 8];
            acc[0][jt] = __builtin_amdgcn_mfma_f32_16x16x32_bf16(a0, b, acc[0][jt], 0, 0, 0);
            acc[1][jt] = __builtin_amdgcn_mfma_f32_16x16x32_bf16(a1, b, acc[1][jt], 0, 0, 0);
        }
    }
    #pragma unroll
    for (int jt = 0; jt < 4; ++jt) {
        int j = wave * 64 + jt * 16 + col;             // 0..255
        float bias = (j < EE) ? agf[j] : bh2f[j - EE];
        u16* dst = (j < EE) ? (g + j) : (h2 + (j - EE));
        #pragma unroll
        for (int mt = 0; mt < 2; ++mt)
            #pragma unroll
            for (int i = 0; i < 4; ++i) {
                long row = n0 + mt * 16 + quad * 4 + i;
                if (row < N_NODES) dst[row * EE] = f2bu(acc[mt][jt][i] + bias);
            }
    }
}

// ---------------------------------------------------------------------------
// Fused gather + relu + Wp-dot + mean (R9 restructure).
// Lane layout: quad=lane>>4 owns k = 16*mt + 4*kq + quad; jb=lane&15 owns
// j-block jb*8..jb*8+7. Gather is dwordx4 (4 rows/instr, 1KB/instr). msg is
// packed bf16 into a per-wave LDS tile [16][68] in MFMA A-frag order; the
// Wp-dot is 16 MFMAs against precomputed hi/lo Wp B-frags (Wp at f32
// accuracy). Mean stays VALU (free: k is the lane-local loop). No transpose
// tail, no per-k shuffles.
// grid N/4, block 256.
// ---------------------------------------------------------------------------
__global__ __launch_bounds__(256) void fused_msg(const int* __restrict__ argmax,
                                                 const u32* __restrict__ g,
                                                 const u32* __restrict__ h2,
                                                 const u16* __restrict__ Wpf,
                                                 const float* __restrict__ bpv,
                                                 float* outpos,
                                                 u32* __restrict__ meanws) {
    __shared__ u32 tile[WAVES][16 * 68];
    int tid = threadIdx.x;
    int lane = tid & 63;
    int wave = __builtin_amdgcn_readfirstlane(tid >> 6);
    int n = blockIdx.x * WAVES + wave;                 // wave-uniform
    int jb = lane & 15, quad = lane >> 4;

    // h2 block for this lane's 8 j's
    uint4 hv = ((const uint4*)(h2 + (long)n * 64))[jb];
    float h0 = bflo(hv.x), h1 = bfhi(hv.x), hA = bflo(hv.y), h3 = bfhi(hv.y),
          h4 = bflo(hv.z), h5 = bfhi(hv.z), h6 = bflo(hv.w), h7 = bfhi(hv.w);

    // Wp B-fragments (hi/lo split), L2-resident
    bf16x8 wpf[2][4];
    #pragma unroll
    for (int s = 0; s < 2; ++s)
        #pragma unroll
        for (int t = 0; t < 4; ++t)
            wpf[s][t] = *(const bf16x8*)&Wpf[(long)s * 2048 + t * 512 + lane * 8];

    // per-lane k-schedule: k = i*4 + quad, i = mt*4+kq
    int rows[8]; float dks[8];
    const int* ap = argmax + (long)n * KK + quad;
    const float* dp = outpos + (long)n * KK + quad;
    #pragma unroll
    for (int i = 0; i < 8; ++i) { rows[i] = ap[i * 4]; dks[i] = dp[i * 4]; }

    float am0 = 0.f, am1 = 0.f, am2 = 0.f, am3 = 0.f,
          am4 = 0.f, am5 = 0.f, am6 = 0.f, am7 = 0.f;
    f32x4 accP[2] = {};
    float bpf = bpv[0];

    #pragma unroll
    for (int mt = 0; mt < 2; ++mt) {
        #pragma unroll
        for (int kq = 0; kq < 4; ++kq) {
            int idx = mt * 4 + kq;
            const u32* gp = g + ((long)rows[idx] << 6);
            uint4 gv = ((const uint4*)gp)[jb];
            float dk = dks[idx];
            float m0 = fmaxf(fmaf(dk, bflo(gv.x), h0), 0.f);
            float m1 = fmaxf(fmaf(dk, bfhi(gv.x), h1), 0.f);
            float m2 = fmaxf(fmaf(dk, bflo(gv.y), hA), 0.f);
            float m3 = fmaxf(fmaf(dk, bfhi(gv.y), h3), 0.f);
            float m4 = fmaxf(fmaf(dk, bflo(gv.z), h4), 0.f);
            float m5 = fmaxf(fmaf(dk, bfhi(gv.z), h5), 0.f);
            float m6 = fmaxf(fmaf(dk, bflo(gv.w), h6), 0.f);
            float m7 = fmaxf(fmaf(dk, bfhi(gv.w), h7), 0.f);
            am0 += m0; am1 += m1; am2 += m2; am3 += m3;
            am4 += m4; am5 += m5; am6 += m6; am7 += m7;
            uint4 pw;
            pw.x = packbf2(m0, m1);
            pw.y = packbf2(m2, m3);
            pw.z = packbf2(m4, m5);
            pw.w = packbf2(m6, m7);
            *(uint4*)&tile[wave][(kq * 4 + quad) * 68 + jb * 4] = pw;
        }
        #pragma unroll
        for (int t = 0; t < 4; ++t) {
            bf16x8 a = *(const bf16x8*)&tile[wave][jb * 68 + t * 16 + quad * 4];
            accP[mt] = __builtin_amdgcn_mfma_f32_16x16x32_bf16(a, wpf[0][t], accP[mt], 0, 0, 0);
            accP[mt] = __builtin_amdgcn_mfma_f32_16x16x32_bf16(a, wpf[1][t], accP[mt], 0, 0, 0);
        }
    }

    // mean over k: combine the 4 quad partials per j
    am0 += __shfl_xor(am0, 16); am0 += __shfl_xor(am0, 32);
    am1 += __shfl_xor(am1, 16); am1 += __shfl_xor(am1, 32);
    am2 += __shfl_xor(am2, 16); am2 += __shfl_xor(am2, 32);
    am3 += __shfl_xor(am3, 16); am3 += __shfl_xor(am3, 32);
    am4 += __shfl_xor(am4, 16); am4 += __shfl_xor(am4, 32);
    am5 += __shfl_xor(am5, 16); am5 += __shfl_xor(am5, 32);
    am6 += __shfl_xor(am6, 16); am6 += __shfl_xor(am6, 32);
    am7 += __shfl_xor(am7, 16); am7 += __shfl_xor(am7, 32);
    if (lane < 16) {
        const float inv = 1.f / KK;
        uint4 mw;
        mw.x = packbf2(am0 * inv, am1 * inv);
        mw.y = packbf2(am2 * inv, am3 * inv);
        mw.z = packbf2(am4 * inv, am5 * inv);
        mw.w = packbf2(am6 * inv, am7 * inv);
        *(uint4*)&meanws[(long)n * 64 + jb * 4] = mw;
    }

    // positions: C layout col=lane&15, row=quad*4+i; col 0 holds the dot
    #pragma unroll
    for (int mt = 0; mt < 2; ++mt) {
        if (jb == 0) {
            float4 o = make_float4(accP[mt][0] + bpf, accP[mt][1] + bpf,
                                   accP[mt][2] + bpf, accP[mt][3] + bpf);
            *(float4*)&outpos[(long)n * KK + mt * 16 + quad * 4] = o;
        }
    }
}

// ---------------------------------------------------------------------------
// MFMA GEMM: out_structure = [mean | ea] @ Ws^T + bs -> f32, overwrites the
// out_structure region. Block: 32 rows x 128 cols, K=256 (8 k-steps),
// 4 waves x (2 m-tiles x 2 j-tiles). A staged bf16 in LDS, stride 132 u32.
// grid ceil(N/32), block 256.
// ---------------------------------------------------------------------------
__global__ __launch_bounds__(256) void out_struct_mfma(const u16* __restrict__ meanws,
                                                       const float* __restrict__ edge_attr,
                                                       const u16* __restrict__ Wstp,
                                                       const float* __restrict__ bs,
                                                       float* __restrict__ outs) {
    __shared__ u32 at[PR * 132];
    int tid = threadIdx.x;
    int n0 = blockIdx.x * PR;
    for (int idx = tid; idx < PR * 64; idx += 256) {   // mean: u32 units, 64/row
        int rr = idx >> 6, c = idx & 63;
        long row = n0 + rr; if (row >= N_NODES) row = N_NODES - 1;
        at[rr * 132 + c] = ((const u32*)meanws)[row * 64 + c];
    }
    for (int idx = tid; idx < PR * 32; idx += 256) {   // ea: float4 units, 32/row
        int rr = idx >> 5, c4 = idx & 31;
        long row = n0 + rr; if (row >= N_NODES) row = N_NODES - 1;
        float4 v = ((const float4*)(edge_attr + row * EE))[c4];
        at[rr * 132 + 64 + 2 * c4]     = packbf2(v.x, v.y);
        at[rr * 132 + 64 + 2 * c4 + 1] = packbf2(v.z, v.w);
    }
    __syncthreads();
    int lane = tid & 63, wave = tid >> 6;
    int col = lane & 15, quad = lane >> 4;
    f32x4 acc[2][2] = {};
    #pragma unroll
    for (int t = 0; t < 8; ++t) {
        bf16x8 a0 = *(const bf16x8*)&at[col * 132 + t * 16 + quad * 4];
        bf16x8 a1 = *(const bf16x8*)&at[(16 + col) * 132 + t * 16 + quad * 4];
        #pragma unroll
        for (int jt = 0; jt < 2; ++jt) {
            int jtg = wave * 2 + jt;
            bf16x8 b = *(const bf16x8*)&Wstp[((long)(t * 8 + jtg) * 64 + lane) * 8];
            acc[0][jt] = __builtin_amdgcn_mfma_f32_16x16x32_bf16(a0, b, acc[0][jt], 0, 0, 0);
            acc[1][jt] = __builtin_amdgcn_mfma_f32_16x16x32_bf16(a1, b, acc[1][jt], 0, 0, 0);
        }
    }
    #pragma unroll
    for (int jt = 0; jt < 2; ++jt) {
        int j = wave * 32 + jt * 16 + col;             // 0..127
        float bias = bs[j];
        #pragma unroll
        for (int mt = 0; mt < 2; ++mt)
            #pragma unroll
            for (int i = 0; i < 4; ++i) {
                long row = n0 + mt * 16 + quad * 4 + i;
                if (row < N_NODES) outs[row * EE + j] = acc[mt][jt][i] + bias;
            }
    }
}

extern "C" void kernel_launch(void* const* d_in, const int* in_sizes, int n_in,
                              void* d_out, int out_size, void* d_ws, size_t ws_size,
                              hipStream_t stream) {
    const float* feature   = (const float*)d_in[0];
    const float* dists_max = (const float*)d_in[1];
    const int* dists_argmax = (const int*)d_in[2];
    const float* edge_attr = (const float*)d_in[3];
    const float* W1 = (const float*)d_in[4];
    const float* b1 = (const float*)d_in[5];
    const float* W2 = (const float*)d_in[6];
    const float* b2 = (const float*)d_in[7];
    const float* Wf = (const float*)d_in[8];
    const float* bf = (const float*)d_in[9];
    const float* Wh = (const float*)d_in[10];
    const float* bh = (const float*)d_in[11];
    const float* Wp = (const float*)d_in[12];
    const float* bp = (const float*)d_in[13];
    const float* Ws = (const float*)d_in[14];
    const float* bs = (const float*)d_in[15];

    float* outpos = (float*)d_out;        // [N,K] f32: d scratch, then pos
    float* outs   = outpos + NK;          // [N,E] f32: g+h2 bf16 scratch, then out_structure
    u16* g  = (u16*)outs;                 // [N,E] bf16  (12.8 MB)
    u16* h2 = g + NE;                     // [N,E] bf16  (12.8 MB)

    // Workspace (same footprint as R5-R8): 0.26 MB f32 + 12.8 MB bf16.
    float* Acm  = (float*)d_ws;           // [EE*EE]  (now: Wp frag area, 8 KB used)
    float* Bcm  = Acm + EE * EE;          // [EE*EE]  (unused)
    float* agf  = Bcm + EE * EE;          // [EE]
    float* bh2f = agf + EE;               // [EE]
    float* Wst  = bh2f + EE;              // [2*EE*EE] area, reused for packs:
    u16* Wghp = (u16*)Wst;                //   64 KB (4*16 frag-tiles)
    u16* Wstp = Wghp + 64 * 512;          //   64 KB (8*8 frag-tiles)
    u16* Wpf  = (u16*)Acm;                //   8 KB  (2 sets x 4 t x 512)
    u16* meanws = (u16*)(Wst + 2 * EE * EE);  // [N*E] bf16 (unchanged offset)

    int gemm_blocks = (N_NODES + PR - 1) / PR;
    prep_pack<<<321, 128, 0, stream>>>(Wh, Wf, bf, bh, Ws, Wp, Wghp, Wstp, Wpf, agf, bh2f);
    dist_mlp<<<(NK + 1023) / 1024, 256, 0, stream>>>(dists_max, W1, b1, W2, b2, outpos);
    proj_gh_mfma<<<gemm_blocks, 256, 0, stream>>>(feature, Wghp, agf, bh2f, g, h2);
    fused_msg<<<N_NODES / WAVES, 256, 0, stream>>>(dists_argmax, (const u32*)g,
                                                   (const u32*)h2, Wpf, bp,
                                                   outpos, (u32*)meanws);
    out_struct_mfma<<<gemm_blocks, 256, 0, stream>>>(meanws, edge_attr, Wstp, bs, outs);
}

// Round 4
// 225.638 us; speedup vs baseline: 1.0168x; 1.0168x over previous
//
#include <hip/hip_runtime.h>
#include <hip/hip_bf16.h>

#define N_NODES 50000
#define KK 32
#define EE 128
#define NK (N_NODES * KK)
#define NE (N_NODES * EE)
#define WAVES 4
#define PR 32   // rows per GEMM block

typedef __hip_bfloat16 bf16;
typedef unsigned int u32;
typedef unsigned short u16;
typedef __attribute__((ext_vector_type(8))) short bf16x8;
typedef __attribute__((ext_vector_type(4))) float f32x4;

__device__ __forceinline__ float bflo(u32 u) { return __uint_as_float(u << 16); }
__device__ __forceinline__ float bfhi(u32 u) { return __uint_as_float(u & 0xFFFF0000u); }
__device__ __forceinline__ u16 f2bu(float x) {
    union { bf16 b; u16 u; } c; c.b = __float2bfloat16(x); return c.u;
}
__device__ __forceinline__ u32 packbf2(float lo, float hi) {
    return (u32)f2bu(lo) | ((u32)f2bu(hi) << 16);
}

// ---------------------------------------------------------------------------
// Merged prep+pack (kept from R9, Wp-frag block dropped): blocks 0..255
// compute A=WhL@Wf / B=WhR@Wf elements and write Wghp frag layout DIRECTLY;
// blocks 256..319 pack Wstp from Ws. grid 320, block 128.
// ---------------------------------------------------------------------------
__global__ void prep_pack(const float* __restrict__ Wh, const float* __restrict__ Wf,
                          const float* __restrict__ bfv, const float* __restrict__ bh,
                          const float* __restrict__ Ws,
                          u16* __restrict__ Wghp, u16* __restrict__ Wstp,
                          float* agf, float* bh2f) {
    int bx = blockIdx.x;
    int tid = threadIdx.x;
    if (bx < 256) {
        int m = bx >> 7;
        int r = bx & 127;
        int c = tid;
        const float* whrow = Wh + (long)r * (2 * EE) + m * EE;
        float acc = 0.f;
        for (int j = 0; j < EE; ++j)
            acc += whrow[j] * Wf[(long)j * EE + c];
        // frag coords: K-index k=c, N-index j=m*128+r
        int jt = (m * EE + r) >> 4, col = r & 15;
        int t = c >> 5, quad = (c >> 3) & 3, jj = c & 7;
        Wghp[((long)(t * 16 + jt)) * 512 + (quad * 16 + col) * 8 + jj] = f2bu(acc);
        if (c == 0) {
            float accb = 0.f;
            for (int j = 0; j < EE; ++j) accb += whrow[j] * bfv[j];
            if (m) bh2f[r] = accb + bh[r];
            else   agf[r] = accb;
        }
    } else {
        int bb = bx - 256, t = bb >> 3, jt = bb & 7;
        for (int f = tid; f < 512; f += 128) {
            int lane = f >> 3, jj = f & 7;
            int col = lane & 15, quad = lane >> 4;
            int r = jt * 16 + col;
            int c = t * 32 + quad * 8 + jj;
            Wstp[(long)bb * 512 + f] = f2bu(Ws[(long)r * (2 * EE) + c]);
        }
    }
}

// ---------------------------------------------------------------------------
// Distance MLP: d(x) = sum_e W2[e]*relu(W1[e]*x + b1[e]) + b2.
// d written f32 into the out_position region of d_out.
// ---------------------------------------------------------------------------
__global__ __launch_bounds__(256) void dist_mlp(const float* __restrict__ dists,
                                                const float* __restrict__ W1,
                                                const float* __restrict__ b1,
                                                const float* __restrict__ W2,
                                                const float* __restrict__ b2v,
                                                float* __restrict__ dst) {
    __shared__ float4 w4[EE];
    int tid = threadIdx.x;
    if (tid < EE) w4[tid] = make_float4(W1[tid], b1[tid], W2[tid], 0.f);
    __syncthreads();
    float b2s = b2v[0];
    int i0 = (blockIdx.x * 256 + tid) * 4;
    float x[4], acc[4];
    #pragma unroll
    for (int j = 0; j < 4; ++j) {
        int i = i0 + j;
        x[j] = (i < NK) ? dists[i] : 0.f;
        acc[j] = b2s;
    }
    for (int e = 0; e < EE; ++e) {
        float4 w = w4[e];
        #pragma unroll
        for (int j = 0; j < 4; ++j)
            acc[j] += w.z * fmaxf(w.x * x[j] + w.y, 0.f);
    }
    #pragma unroll
    for (int j = 0; j < 4; ++j) {
        int i = i0 + j;
        if (i < NK) dst[i] = acc[j];
    }
}

// ---------------------------------------------------------------------------
// MFMA GEMM: [g|h2] = feature @ [A;B]^T + bias  -> bf16 into out_structure
// region. Block: 32 rows x 256 cols, 4 waves x (2 m-tiles x 4 j-tiles).
// Feature staged bf16 in LDS, row stride 68 u32 (2-way bank alias = free).
// grid ceil(N/32), block 256.
// ---------------------------------------------------------------------------
__global__ __launch_bounds__(256) void proj_gh_mfma(const float* __restrict__ feature,
                                                    const u16* __restrict__ Wghp,
                                                    const float* __restrict__ agf,
                                                    const float* __restrict__ bh2f,
                                                    u16* __restrict__ g,
                                                    u16* __restrict__ h2) {
    __shared__ u32 ft[PR * 68];
    int tid = threadIdx.x;
    int n0 = blockIdx.x * PR;
    for (int idx = tid; idx < PR * 32; idx += 256) {   // float4 units, 32/row
        int rr = idx >> 5, c4 = idx & 31;
        long row = n0 + rr; if (row >= N_NODES) row = N_NODES - 1;
        float4 v = ((const float4*)(feature + row * EE))[c4];
        ft[rr * 68 + 2 * c4]     = packbf2(v.x, v.y);
        ft[rr * 68 + 2 * c4 + 1] = packbf2(v.z, v.w);
    }
    __syncthreads();
    int lane = tid & 63, wave = tid >> 6;
    int col = lane & 15, quad = lane >> 4;
    f32x4 acc[2][4] = {};
    #pragma unroll
    for (int t = 0; t < 4; ++t) {
        bf16x8 a0 = *(const bf16x8*)&ft[col * 68 + t * 16 + quad * 4];
        bf16x8 a1 = *(const bf16x8*)&ft[(16 + col) * 68 + t * 16 + quad * 4];
        #pragma unroll
        for (int jt = 0; jt < 4; ++jt) {
            int jtg = wave * 4 + jt;
            bf16x8 b = *(const bf16x8*)&Wghp[((long)(t * 16 + jtg) * 64 + lane) * 8];
            acc[0][jt] = __builtin_amdgcn_mfma_f32_16x16x32_bf16(a0, b, acc[0][jt], 0, 0, 0);
            acc[1][jt] = __builtin_amdgcn_mfma_f32_16x16x32_bf16(a1, b, acc[1][jt], 0, 0, 0);
        }
    }
    #pragma unroll
    for (int jt = 0; jt < 4; ++jt) {
        int j = wave * 64 + jt * 16 + col;             // 0..255
        float bias = (j < EE) ? agf[j] : bh2f[j - EE];
        u16* dst = (j < EE) ? (g + j) : (h2 + (j - EE));
        #pragma unroll
        for (int mt = 0; mt < 2; ++mt)
            #pragma unroll
            for (int i = 0; i < 4; ++i) {
                long row = n0 + mt * 16 + quad * 4 + i;
                if (row < N_NODES) dst[row * EE] = f2bu(acc[mt][jt][i] + bias);
            }
    }
}

// ---------------------------------------------------------------------------
// Fused gather + relu + Wp-dot + mean (R10 = R8 proven structure + d-row
// register preload). Wave-uniform n -> argmax row scalarizes (s_load),
// readfirstlane(row) -> SALU gather address + saddr global_load_dword.
// d row hoisted to 8 float4 preloads (removes 24 VMEM issues from the loop,
// frees the loop for deeper gather pipelining). Arithmetic bit-identical
// to R8. grid N/4, block 256.
// ---------------------------------------------------------------------------
__global__ __launch_bounds__(256) void fused_msg(const int* __restrict__ argmax,
                                                 const u32* __restrict__ g,
                                                 const u32* __restrict__ h2,
                                                 const float* __restrict__ Wp,
                                                 const float* __restrict__ bpv,
                                                 float* outpos,
                                                 u32* __restrict__ meanws) {
    __shared__ u32 tile[WAVES][KK / 2][65];
    int tid = threadIdx.x;
    int lane = tid & 63;
    int wave = __builtin_amdgcn_readfirstlane(tid >> 6);
    int n = blockIdx.x * WAVES + wave;                 // wave-uniform

    const int* arow = argmax + (long)n * KK;           // uniform -> SMEM loads

    // preload the d row (lane-uniform) into registers, fully static indexing
    float dvf[KK];
    {
        const float4* dr4 = (const float4*)(outpos + (long)n * KK);
        #pragma unroll
        for (int q = 0; q < 8; ++q) {
            float4 v = dr4[q];
            dvf[4 * q + 0] = v.x; dvf[4 * q + 1] = v.y;
            dvf[4 * q + 2] = v.z; dvf[4 * q + 3] = v.w;
        }
    }

    u32 hu = h2[(long)n * (EE / 2) + lane];
    float h0 = bflo(hu), h1 = bfhi(hu);
    float2 wpv = ((const float2*)Wp)[lane];
    float bpf = bpv[0];

    float acc0 = 0.f, acc1 = 0.f;
    float ppe = 0.f;
    #pragma unroll
    for (int k = 0; k < KK; ++k) {
        int row = __builtin_amdgcn_readfirstlane(arow[k]);  // scalar row
        float dk = dvf[k];                                   // in-register
        const u32* gp = g + (long)row * (EE / 2);            // SALU address
        u32 gu = gp[lane];                                   // saddr + v_lane4
        float m0 = fmaxf(fmaf(dk, bflo(gu), h0), 0.f);
        float m1 = fmaxf(fmaf(dk, bfhi(gu), h1), 0.f);
        acc0 += m0;
        acc1 += m1;
        float p = fmaf(m1, wpv.y, m0 * wpv.x);
        if (k & 1) tile[wave][k >> 1][lane] = packbf2(ppe, p);
        else       ppe = p;
    }
    meanws[(long)n * (EE / 2) + lane] = packbf2(acc0 * (1.f / KK), acc1 * (1.f / KK));

    int d = lane & 15;
    int j0 = (lane >> 4) * 16;
    float s0 = 0.f, s1 = 0.f;
    #pragma unroll
    for (int i = 0; i < 16; ++i) {
        u32 v = tile[wave][d][j0 + i];
        s0 += bflo(v);
        s1 += bfhi(v);
    }
    s0 += __shfl_xor(s0, 16);
    s1 += __shfl_xor(s1, 16);
    s0 += __shfl_xor(s0, 32);
    s1 += __shfl_xor(s1, 32);
    if (lane < 16) {
        float2 o = make_float2(s0 + bpf, s1 + bpf);
        *(float2*)&outpos[(long)n * KK + 2 * d] = o;
    }
}

// ---------------------------------------------------------------------------
// MFMA GEMM: out_structure = [mean | ea] @ Ws^T + bs -> f32, overwrites the
// out_structure region. Block: 32 rows x 128 cols, K=256 (8 k-steps),
// 4 waves x (2 m-tiles x 2 j-tiles). A staged bf16 in LDS, stride 132 u32.
// grid ceil(N/32), block 256.
// ---------------------------------------------------------------------------
__global__ __launch_bounds__(256) void out_struct_mfma(const u16* __restrict__ meanws,
                                                       const float* __restrict__ edge_attr,
                                                       const u16* __restrict__ Wstp,
                                                       const float* __restrict__ bs,
                                                       float* __restrict__ outs) {
    __shared__ u32 at[PR * 132];
    int tid = threadIdx.x;
    int n0 = blockIdx.x * PR;
    for (int idx = tid; idx < PR * 64; idx += 256) {   // mean: u32 units, 64/row
        int rr = idx >> 6, c = idx & 63;
        long row = n0 + rr; if (row >= N_NODES) row = N_NODES - 1;
        at[rr * 132 + c] = ((const u32*)meanws)[row * 64 + c];
    }
    for (int idx = tid; idx < PR * 32; idx += 256) {   // ea: float4 units, 32/row
        int rr = idx >> 5, c4 = idx & 31;
        long row = n0 + rr; if (row >= N_NODES) row = N_NODES - 1;
        float4 v = ((const float4*)(edge_attr + row * EE))[c4];
        at[rr * 132 + 64 + 2 * c4]     = packbf2(v.x, v.y);
        at[rr * 132 + 64 + 2 * c4 + 1] = packbf2(v.z, v.w);
    }
    __syncthreads();
    int lane = tid & 63, wave = tid >> 6;
    int col = lane & 15, quad = lane >> 4;
    f32x4 acc[2][2] = {};
    #pragma unroll
    for (int t = 0; t < 8; ++t) {
        bf16x8 a0 = *(const bf16x8*)&at[col * 132 + t * 16 + quad * 4];
        bf16x8 a1 = *(const bf16x8*)&at[(16 + col) * 132 + t * 16 + quad * 4];
        #pragma unroll
        for (int jt = 0; jt < 2; ++jt) {
            int jtg = wave * 2 + jt;
            bf16x8 b = *(const bf16x8*)&Wstp[((long)(t * 8 + jtg) * 64 + lane) * 8];
            acc[0][jt] = __builtin_amdgcn_mfma_f32_16x16x32_bf16(a0, b, acc[0][jt], 0, 0, 0);
            acc[1][jt] = __builtin_amdgcn_mfma_f32_16x16x32_bf16(a1, b, acc[1][jt], 0, 0, 0);
        }
    }
    #pragma unroll
    for (int jt = 0; jt < 2; ++jt) {
        int j = wave * 32 + jt * 16 + col;             // 0..127
        float bias = bs[j];
        #pragma unroll
        for (int mt = 0; mt < 2; ++mt)
            #pragma unroll
            for (int i = 0; i < 4; ++i) {
                long row = n0 + mt * 16 + quad * 4 + i;
                if (row < N_NODES) outs[row * EE + j] = acc[mt][jt][i] + bias;
            }
    }
}

extern "C" void kernel_launch(void* const* d_in, const int* in_sizes, int n_in,
                              void* d_out, int out_size, void* d_ws, size_t ws_size,
                              hipStream_t stream) {
    const float* feature   = (const float*)d_in[0];
    const float* dists_max = (const float*)d_in[1];
    const int* dists_argmax = (const int*)d_in[2];
    const float* edge_attr = (const float*)d_in[3];
    const float* W1 = (const float*)d_in[4];
    const float* b1 = (const float*)d_in[5];
    const float* W2 = (const float*)d_in[6];
    const float* b2 = (const float*)d_in[7];
    const float* Wf = (const float*)d_in[8];
    const float* bf = (const float*)d_in[9];
    const float* Wh = (const float*)d_in[10];
    const float* bh = (const float*)d_in[11];
    const float* Wp = (const float*)d_in[12];
    const float* bp = (const float*)d_in[13];
    const float* Ws = (const float*)d_in[14];
    const float* bs = (const float*)d_in[15];

    float* outpos = (float*)d_out;        // [N,K] f32: d scratch, then pos
    float* outs   = outpos + NK;          // [N,E] f32: g+h2 bf16 scratch, then out_structure
    u16* g  = (u16*)outs;                 // [N,E] bf16  (12.8 MB)
    u16* h2 = g + NE;                     // [N,E] bf16  (12.8 MB)

    // Workspace (same footprint as R5-R9): 0.26 MB f32 + 12.8 MB bf16.
    float* Acm  = (float*)d_ws;           // [EE*EE]  (unused, layout anchor)
    float* Bcm  = Acm + EE * EE;          // [EE*EE]  (unused)
    float* agf  = Bcm + EE * EE;          // [EE]
    float* bh2f = agf + EE;               // [EE]
    float* Wst  = bh2f + EE;              // [2*EE*EE] area, reused for packs:
    u16* Wghp = (u16*)Wst;                //   64 KB (4*16 frag-tiles)
    u16* Wstp = Wghp + 64 * 512;          //   64 KB (8*8 frag-tiles)
    u16* meanws = (u16*)(Wst + 2 * EE * EE);  // [N*E] bf16 (unchanged offset)

    int gemm_blocks = (N_NODES + PR - 1) / PR;
    prep_pack<<<320, 128, 0, stream>>>(Wh, Wf, bf, bh, Ws, Wghp, Wstp, agf, bh2f);
    dist_mlp<<<(NK + 1023) / 1024, 256, 0, stream>>>(dists_max, W1, b1, W2, b2, outpos);
    proj_gh_mfma<<<gemm_blocks, 256, 0, stream>>>(feature, Wghp, agf, bh2f, g, h2);
    fused_msg<<<N_NODES / WAVES, 256, 0, stream>>>(dists_argmax, (const u32*)g,
                                                   (const u32*)h2, Wp, bp,
                                                   outpos, (u32*)meanws);
    out_struct_mfma<<<gemm_blocks, 256, 0, stream>>>(meanws, edge_attr, Wstp, bs, outs);
}